// Round 2
// baseline (897.355 us; speedup 1.0000x reference)
//
#include <hip/hip_runtime.h>
#include <hip/hip_bf16.h>

// Problem: B=64, S=512, D=768, H=512, T=37
#define Bb 64
#define Ss 512
#define Dd 768
#define Hh 512
#define Tt 37

typedef unsigned short u16;
typedef unsigned int u32;
typedef __bf16 bf16x8 __attribute__((ext_vector_type(8)));
typedef float f32x4 __attribute__((ext_vector_type(4)));

__device__ __forceinline__ u16 f2bf(float x) {
  union { float f; u32 u; } v; v.f = x;
  u32 r = v.u + 0x7fffu + ((v.u >> 16) & 1u);   // RNE
  return (u16)(r >> 16);
}
__device__ __forceinline__ float bf2f(u16 h) {
  union { u32 u; float f; } v; v.u = ((u32)h) << 16;
  return v.f;
}
// pack 2 floats -> hi u32 (2 bf16), residual lo u32 (2 bf16)
__device__ __forceinline__ u32 pack2(float a, float b, u32& lo) {
  u16 ha = f2bf(a), hb = f2bf(b);
  float ra = a - bf2f(ha), rb = b - bf2f(hb);
  lo = (u32)f2bf(ra) | ((u32)f2bf(rb) << 16);
  return (u32)ha | ((u32)hb << 16);
}
__device__ __forceinline__ float rdlane(float v, int i) {
  return __uint_as_float(__builtin_amdgcn_readlane(__float_as_uint(v), i));
}
union U4BF8 { uint4 u; bf16x8 v; };

// ---------------- prep: split X, transpose+split W1/W2, init logits=b2 ----------------
#define PX (Bb * Ss * Dd / 8 / 256)        // 12288 blocks: X split, 8 elems/thread
#define PW ((Hh * Dd + 255) / 256)         // 1536 blocks: weights
#define PZ ((Bb * Ss * Tt + 255) / 256)    // 4736 blocks: logits = b2
__global__ void prep_all(const float* __restrict__ X, const float* __restrict__ W1,
                         const float* __restrict__ W2, const float* __restrict__ b2,
                         u16* __restrict__ xh, u16* __restrict__ xl,
                         u16* __restrict__ w1h, u16* __restrict__ w1l,
                         u16* __restrict__ w2h, u16* __restrict__ w2l,
                         float* __restrict__ logits) {
  const int bid = blockIdx.x, t = threadIdx.x;
  if (bid < PX) {
    int base = (bid * 256 + t) * 8;
    float4 v0 = *(const float4*)(X + base);
    float4 v1 = *(const float4*)(X + base + 4);
    float v[8] = {v0.x, v0.y, v0.z, v0.w, v1.x, v1.y, v1.z, v1.w};
    u32 hh[4], ll[4];
#pragma unroll
    for (int i = 0; i < 4; ++i) hh[i] = pack2(v[2 * i], v[2 * i + 1], ll[i]);
    *(uint4*)(xh + base) = make_uint4(hh[0], hh[1], hh[2], hh[3]);
    *(uint4*)(xl + base) = make_uint4(ll[0], ll[1], ll[2], ll[3]);
  } else if (bid < PX + PW) {
    int idx = (bid - PX) * 256 + t;
    if (idx < Hh * Dd) {        // W1 [768][512] -> W1t hi/lo [512][768]
      int n = idx / Dd, k = idx % Dd;
      u32 lo; u32 hi = pack2(W1[k * Hh + n], 0.f, lo);
      w1h[idx] = (u16)hi; w1l[idx] = (u16)lo;
    }
    if (idx < 48 * Hh) {        // W2 [512][37] -> W2t hi/lo [48][512], pad rows 37..47
      int n = idx / Hh, k = idx % Hh;
      float x = (n < Tt) ? W2[k * Tt + n] : 0.0f;
      u32 lo; u32 hi = pack2(x, 0.f, lo);
      w2h[idx] = (u16)hi; w2l[idx] = (u16)lo;
    }
  } else {
    int idx = (bid - PX - PW) * 256 + t;
    if (idx < Bb * Ss * Tt) logits[idx] = b2[idx % Tt];
  }
}

// ---------------- fused GEMM: logits += relu(X@W1+b1) @ W2, bf16x3 MFMA ----------------
// grid 1024 = 256 m-tiles x 4 n-tiles; 256 threads; tile 128x128; fused W2 epilogue.
__global__ __launch_bounds__(256, 2) void gemm_fused(
    const u16* __restrict__ xh, const u16* __restrict__ xl,
    const u16* __restrict__ w1h, const u16* __restrict__ w1l,
    const float* __restrict__ b1, const u16* __restrict__ w2h,
    const u16* __restrict__ w2l, float* __restrict__ logits) {
  __shared__ __align__(16) char smem[40960];
  u16* As_h = (u16*)smem;               // 128 x pitch40 u16 = 10240 B
  u16* As_l = (u16*)(smem + 10240);
  u16* Bs_h = (u16*)(smem + 20480);
  u16* Bs_l = (u16*)(smem + 30720);
  float* Hs = (float*)smem;             // epilogue overlay: 128 x pitch36 f32 = 18432 B
  u16* W2s_h = (u16*)(smem + 20480);    // epilogue overlay: 48 x pitch40 u16
  u16* W2s_l = (u16*)(smem + 30720);

  const int t = threadIdx.x;
  const int tile_m = blockIdx.x >> 2, tile_n = blockIdx.x & 3;
  const int m0 = tile_m * 128, n0 = tile_n * 128;
  const int w = t >> 6, l = t & 63;
  const int wr = w >> 1, wc = w & 1;
  const int lm = l & 15, lk = (l >> 4) * 8, q = l >> 4;
  const int srow = t >> 1, skh = (t & 1) * 16;

  const u16* Agh = xh + (m0 + srow) * Dd + skh;
  const u16* Agl = xl + (m0 + srow) * Dd + skh;
  const u16* Bgh = w1h + (n0 + srow) * Dd + skh;
  const u16* Bgl = w1l + (n0 + srow) * Dd + skh;

  float b1v[4];
#pragma unroll
  for (int n = 0; n < 4; ++n) b1v[n] = b1[n0 + wc * 64 + n * 16 + lm];

  f32x4 acc[4][4] = {};

#pragma unroll 1
  for (int kt = 0; kt < Dd / 32; ++kt) {
    const int k0 = kt * 32;
    uint4 ah0 = *(const uint4*)(Agh + k0), ah1 = *(const uint4*)(Agh + k0 + 8);
    uint4 al0 = *(const uint4*)(Agl + k0), al1 = *(const uint4*)(Agl + k0 + 8);
    uint4 bh0 = *(const uint4*)(Bgh + k0), bh1 = *(const uint4*)(Bgh + k0 + 8);
    uint4 bl0 = *(const uint4*)(Bgl + k0), bl1 = *(const uint4*)(Bgl + k0 + 8);
    __syncthreads();  // previous iteration's frag reads done
    *(uint4*)&As_h[srow * 40 + skh] = ah0; *(uint4*)&As_h[srow * 40 + skh + 8] = ah1;
    *(uint4*)&As_l[srow * 40 + skh] = al0; *(uint4*)&As_l[srow * 40 + skh + 8] = al1;
    *(uint4*)&Bs_h[srow * 40 + skh] = bh0; *(uint4*)&Bs_h[srow * 40 + skh + 8] = bh1;
    *(uint4*)&Bs_l[srow * 40 + skh] = bl0; *(uint4*)&Bs_l[srow * 40 + skh + 8] = bl1;
    __syncthreads();

    bf16x8 fah[4], fal[4], fbh[4], fbl[4];
#pragma unroll
    for (int m = 0; m < 4; ++m) {
      int ar = wr * 64 + m * 16 + lm;
      fah[m] = *(const bf16x8*)&As_h[ar * 40 + lk];
      fal[m] = *(const bf16x8*)&As_l[ar * 40 + lk];
    }
#pragma unroll
    for (int n = 0; n < 4; ++n) {
      int br = wc * 64 + n * 16 + lm;
      fbh[n] = *(const bf16x8*)&Bs_h[br * 40 + lk];
      fbl[n] = *(const bf16x8*)&Bs_l[br * 40 + lk];
    }
#pragma unroll
    for (int m = 0; m < 4; ++m)
#pragma unroll
      for (int n = 0; n < 4; ++n) {
        acc[m][n] = __builtin_amdgcn_mfma_f32_16x16x32_bf16(fah[m], fbh[n], acc[m][n], 0, 0, 0);
        acc[m][n] = __builtin_amdgcn_mfma_f32_16x16x32_bf16(fah[m], fbl[n], acc[m][n], 0, 0, 0);
        acc[m][n] = __builtin_amdgcn_mfma_f32_16x16x32_bf16(fal[m], fbh[n], acc[m][n], 0, 0, 0);
      }
  }

  // ---- fused epilogue: h-tile (bias+relu) -> Hs -> h@W2 chunk -> acc2 ----
  f32x4 acc2[2][3] = {};
#pragma unroll 1
  for (int c = 0; c < 4; ++c) {
    __syncthreads();  // protect last k-iter frag reads / previous c's Hs reads
    if (wc == (c >> 1)) {
#pragma unroll
      for (int nn = 0; nn < 2; ++nn) {
        int n = (c & 1) * 2 + nn;
        int k2 = n * 16 + lm - (c & 1) * 32;   // 0..31
#pragma unroll
        for (int m = 0; m < 4; ++m)
#pragma unroll
          for (int r = 0; r < 4; ++r) {
            int row = wr * 64 + m * 16 + q * 4 + r;
            Hs[row * 36 + k2] = fmaxf(acc[m][n][r] + b1v[n], 0.0f);
          }
      }
    }
    if (t < 192) {  // stage W2 chunk: rows 0..47 (tags), k-cols n0+c*32..+31
      int rr = t >> 2, kk = (t & 3) * 8;
      *(uint4*)&W2s_h[rr * 40 + kk] = *(const uint4*)(w2h + rr * Hh + n0 + c * 32 + kk);
      *(uint4*)&W2s_l[rr * 40 + kk] = *(const uint4*)(w2l + rr * Hh + n0 + c * 32 + kk);
    }
    __syncthreads();
#pragma unroll
    for (int j = 0; j < 2; ++j) {
      int mm = w * 2 + j;
      f32x4 h0 = *(const f32x4*)&Hs[(mm * 16 + lm) * 36 + lk];
      f32x4 h1 = *(const f32x4*)&Hs[(mm * 16 + lm) * 36 + lk + 4];
      float hv[8] = {h0[0], h0[1], h0[2], h0[3], h1[0], h1[1], h1[2], h1[3]};
      U4BF8 ah, al;
      u32 ll2[4], hh2[4];
#pragma unroll
      for (int i = 0; i < 4; ++i) hh2[i] = pack2(hv[2 * i], hv[2 * i + 1], ll2[i]);
      ah.u = make_uint4(hh2[0], hh2[1], hh2[2], hh2[3]);
      al.u = make_uint4(ll2[0], ll2[1], ll2[2], ll2[3]);
#pragma unroll
      for (int n2 = 0; n2 < 3; ++n2) {
        bf16x8 wh = *(const bf16x8*)&W2s_h[(n2 * 16 + lm) * 40 + lk];
        bf16x8 wl = *(const bf16x8*)&W2s_l[(n2 * 16 + lm) * 40 + lk];
        acc2[j][n2] = __builtin_amdgcn_mfma_f32_16x16x32_bf16(ah.v, wh, acc2[j][n2], 0, 0, 0);
        acc2[j][n2] = __builtin_amdgcn_mfma_f32_16x16x32_bf16(ah.v, wl, acc2[j][n2], 0, 0, 0);
        acc2[j][n2] = __builtin_amdgcn_mfma_f32_16x16x32_bf16(al.v, wh, acc2[j][n2], 0, 0, 0);
      }
    }
  }

  // logits partial: atomic accumulate (logits pre-initialized to b2)
#pragma unroll
  for (int j = 0; j < 2; ++j)
#pragma unroll
    for (int n2 = 0; n2 < 3; ++n2) {
      int col = n2 * 16 + lm;
      if (col < Tt) {
#pragma unroll
        for (int r = 0; r < 4; ++r) {
          int row = m0 + (w * 2 + j) * 16 + q * 4 + r;
          atomicAdd(logits + row * Tt + col, acc2[j][n2][r]);
        }
      }
    }
}

// ---------------- CRF forward + gold, one wave per batch elem ----------------
// readlane-broadcast matvec; rescale point = alpha[lane0] (spread across tags is O(1))
__global__ __launch_bounds__(64) void crf_kernel(
    const float* __restrict__ logits, const void* __restrict__ maskp,
    const int* __restrict__ labels, const float* __restrict__ trans,
    const float* __restrict__ start_t, const float* __restrict__ end_t,
    float* __restrict__ part) {
  const int b = blockIdx.x, l = threadIdx.x;
  const unsigned char* m8 = (const unsigned char*)maskp;
  const int* m32 = (const int*)maskp;
  // mask[0][1] is always true (lengths >= 256): u8 layout -> byte1 != 0; i32 -> byte1 == 0.
  const bool is_u8 = (m8[1] != 0);

  int cnt = 0;
#pragma unroll
  for (int s = l; s < Ss; s += 64) {
    int mv = is_u8 ? (int)m8[b * Ss + s] : m32[b * Ss + s];
    cnt += (mv != 0) ? 1 : 0;
  }
#pragma unroll
  for (int o = 32; o > 0; o >>= 1) cnt += __shfl_xor(cnt, o, 64);
  const int len = cnt;  // mask monotone: mask[s] == (s < len)

  const int* labs = labels + b * Ss;
  float g = 0.0f;
#pragma unroll
  for (int s = l; s < Ss; s += 64) {
    if (s < len) {
      int lab = labs[s];
      g += logits[(b * Ss + s) * Tt + lab];
      if (s + 1 < len) g += trans[lab * Tt + labs[s + 1]];
    }
  }
#pragma unroll
  for (int o = 32; o > 0; o >>= 1) g += __shfl_xor(g, o, 64);
  g += start_t[labs[0]] + end_t[labs[len - 1]];

  float Ecol[Tt];  // Ecol[i] = exp(trans[i][l])
#pragma unroll
  for (int i = 0; i < Tt; ++i)
    Ecol[i] = (l < Tt) ? __expf(trans[i * Tt + l]) : 0.0f;

  const float* lg = logits + b * Ss * Tt;
  float alpha = (l < Tt) ? (start_t[l] + lg[l]) : -INFINITY;
  float em_next = (l < Tt) ? lg[Tt + l] : 0.0f;

  for (int step = 1; step < len; ++step) {
    float em = em_next;
    int nxt = (step + 1 < len) ? step + 1 : len - 1;
    em_next = (l < Tt) ? lg[nxt * Tt + l] : 0.0f;   // prefetch: hidden under matvec
    float a0 = __uint_as_float(__builtin_amdgcn_readfirstlane(__float_as_uint(alpha)));
    float u = __expf(alpha - a0);   // lane0 -> 1; spread O(1), no overflow risk
    float s0 = 0.f, s1 = 0.f, s2 = 0.f, s3 = 0.f;
#pragma unroll
    for (int i = 0; i < 36; i += 4) {
      s0 = fmaf(rdlane(u, i + 0), Ecol[i + 0], s0);
      s1 = fmaf(rdlane(u, i + 1), Ecol[i + 1], s1);
      s2 = fmaf(rdlane(u, i + 2), Ecol[i + 2], s2);
      s3 = fmaf(rdlane(u, i + 3), Ecol[i + 3], s3);
    }
    s0 = fmaf(rdlane(u, 36), Ecol[36], s0);
    float sj = (s0 + s1) + (s2 + s3);
    alpha = a0 + __logf(sj) + em;   // lanes >= 37: sj==0 -> -inf (stay dead)
  }

  float v = (l < Tt) ? (alpha + end_t[l]) : -INFINITY;
  float M2 = v;
#pragma unroll
  for (int o = 32; o > 0; o >>= 1) M2 = fmaxf(M2, __shfl_xor(M2, o, 64));
  float e = __expf(v - M2);
#pragma unroll
  for (int o = 32; o > 0; o >>= 1) e += __shfl_xor(e, o, 64);
  float logZ = M2 + __logf(e);

  if (l == 0) part[b] = logZ - g;
}

__global__ __launch_bounds__(64) void finalize_kernel(const float* __restrict__ part,
                                                      float* __restrict__ out) {
  float v = part[threadIdx.x];
#pragma unroll
  for (int o = 32; o > 0; o >>= 1) v += __shfl_xor(v, o, 64);
  if (threadIdx.x == 0) out[0] = v * (1.0f / (float)Bb);
}

extern "C" void kernel_launch(void* const* d_in, const int* in_sizes, int n_in,
                              void* d_out, int out_size, void* d_ws, size_t ws_size,
                              hipStream_t stream) {
  const float* X       = (const float*)d_in[0];
  const void*  maskp   = d_in[1];
  const int*   labels  = (const int*)d_in[2];
  const float* W1      = (const float*)d_in[3];
  const float* b1      = (const float*)d_in[4];
  const float* W2      = (const float*)d_in[5];
  const float* b2      = (const float*)d_in[6];
  const float* trans   = (const float*)d_in[7];
  const float* start_t = (const float*)d_in[8];
  const float* end_t   = (const float*)d_in[9];
  float* out = (float*)d_out;

  char* ws = (char*)d_ws;
  size_t off = 0;
  u16* w1h = (u16*)(ws + off); off += (size_t)Hh * Dd * 2;          // 768 KB
  u16* w1l = (u16*)(ws + off); off += (size_t)Hh * Dd * 2;
  u16* w2h = (u16*)(ws + off); off += (size_t)48 * Hh * 2;          // 48 KB
  u16* w2l = (u16*)(ws + off); off += (size_t)48 * Hh * 2;
  u16* xh  = (u16*)(ws + off); off += (size_t)Bb * Ss * Dd * 2;     // 48 MB
  u16* xl  = (u16*)(ws + off); off += (size_t)Bb * Ss * Dd * 2;
  float* logits = (float*)(ws + off); off += (size_t)Bb * Ss * Tt * 4;  // 4.6 MB
  float* part = (float*)(ws + off); off += 256;

  prep_all<<<PX + PW + PZ, 256, 0, stream>>>(X, W1, W2, b2, xh, xl, w1h, w1l, w2h, w2l, logits);
  gemm_fused<<<(Bb * Ss / 128) * (Hh / 128), 256, 0, stream>>>(xh, xl, w1h, w1l, b1, w2h, w2l, logits);
  crf_kernel<<<Bb, 64, 0, stream>>>(logits, maskp, labels, trans, start_t, end_t, part);
  finalize_kernel<<<1, 64, 0, stream>>>(part, out);
}

// Round 7
// 394.309 us; speedup vs baseline: 2.2758x; 2.2758x over previous
//
#include <hip/hip_runtime.h>
#include <hip/hip_bf16.h>

// Problem: B=64, S=512, D=768, H=512, T=37
#define Bb 64
#define Ss 512
#define Dd 768
#define Hh 512
#define Tt 37

typedef unsigned short u16;
typedef unsigned int u32;
typedef __bf16 bf16x8 __attribute__((ext_vector_type(8)));
typedef float f32x4 __attribute__((ext_vector_type(4)));

__device__ __forceinline__ u16 f2bf(float x) {
  union { float f; u32 u; } v; v.f = x;
  u32 r = v.u + 0x7fffu + ((v.u >> 16) & 1u);   // RNE
  return (u16)(r >> 16);
}
__device__ __forceinline__ float bf2f(u16 h) {
  union { u32 u; float f; } v; v.u = ((u32)h) << 16;
  return v.f;
}
// pack 2 floats -> hi u32 (2 bf16), residual lo u32 (2 bf16)
__device__ __forceinline__ u32 pack2(float a, float b, u32& lo) {
  u16 ha = f2bf(a), hb = f2bf(b);
  float ra = a - bf2f(ha), rb = b - bf2f(hb);
  lo = (u32)f2bf(ra) | ((u32)f2bf(rb) << 16);
  return (u32)ha | ((u32)hb << 16);
}
__device__ __forceinline__ float rdlane(float v, int i) {
  return __uint_as_float(__builtin_amdgcn_readlane(__float_as_uint(v), i));
}
union U4BF8 { uint4 u; bf16x8 v; };

// ---------------- prep: split X, transpose+split W1/W2, init logits=b2, zero out ----------------
#define PX (Bb * Ss * Dd / 8 / 256)        // 12288 blocks: X split, 8 elems/thread
#define PW ((Hh * Dd + 255) / 256)         // 1536 blocks: weights
#define PZ ((Bb * Ss * Tt + 255) / 256)    // 4736 blocks: logits = b2
__global__ void prep_all(const float* __restrict__ X, const float* __restrict__ W1,
                         const float* __restrict__ W2, const float* __restrict__ b2,
                         u16* __restrict__ xh, u16* __restrict__ xl,
                         u16* __restrict__ w1h, u16* __restrict__ w1l,
                         u16* __restrict__ w2h, u16* __restrict__ w2l,
                         float* __restrict__ logits, float* __restrict__ out) {
  const int bid = blockIdx.x, t = threadIdx.x;
  if (bid == 0 && t == 0) out[0] = 0.0f;   // crf accumulates into out via atomics
  if (bid < PX) {
    int base = (bid * 256 + t) * 8;
    float4 v0 = *(const float4*)(X + base);
    float4 v1 = *(const float4*)(X + base + 4);
    float v[8] = {v0.x, v0.y, v0.z, v0.w, v1.x, v1.y, v1.z, v1.w};
    u32 hh[4], ll[4];
#pragma unroll
    for (int i = 0; i < 4; ++i) hh[i] = pack2(v[2 * i], v[2 * i + 1], ll[i]);
    *(uint4*)(xh + base) = make_uint4(hh[0], hh[1], hh[2], hh[3]);
    *(uint4*)(xl + base) = make_uint4(ll[0], ll[1], ll[2], ll[3]);
  } else if (bid < PX + PW) {
    int idx = (bid - PX) * 256 + t;
    if (idx < Hh * Dd) {        // W1 [768][512] -> W1t hi/lo [512][768]
      int n = idx / Dd, k = idx % Dd;
      u32 lo; u32 hi = pack2(W1[k * Hh + n], 0.f, lo);
      w1h[idx] = (u16)hi; w1l[idx] = (u16)lo;
    }
    if (idx < 48 * Hh) {        // W2 [512][37] -> W2t hi/lo [48][512], pad rows 37..47
      int n = idx / Hh, k = idx % Hh;
      float x = (n < Tt) ? W2[k * Tt + n] : 0.0f;
      u32 lo; u32 hi = pack2(x, 0.f, lo);
      w2h[idx] = (u16)hi; w2l[idx] = (u16)lo;
    }
  } else {
    int idx = (bid - PX - PW) * 256 + t;
    if (idx < Bb * Ss * Tt) logits[idx] = b2[idx % Tt];
  }
}

// ---------------- fused GEMM: logits += relu(X@W1+b1) @ W2, bf16x3 MFMA ----------------
// grid 1024 = 256 m-tiles x 4 n-tiles; 256 threads; tile 128x128; fused W2 epilogue.
__global__ __launch_bounds__(256, 2) void gemm_fused(
    const u16* __restrict__ xh, const u16* __restrict__ xl,
    const u16* __restrict__ w1h, const u16* __restrict__ w1l,
    const float* __restrict__ b1, const u16* __restrict__ w2h,
    const u16* __restrict__ w2l, float* __restrict__ logits) {
  __shared__ __align__(16) char smem[40960];
  u16* As_h = (u16*)smem;               // 128 x pitch40 u16 = 10240 B
  u16* As_l = (u16*)(smem + 10240);
  u16* Bs_h = (u16*)(smem + 20480);
  u16* Bs_l = (u16*)(smem + 30720);
  float* Hs = (float*)smem;             // epilogue overlay: 128 x pitch36 f32 = 18432 B
  u16* W2s_h = (u16*)(smem + 20480);    // epilogue overlay: 48 x pitch40 u16
  u16* W2s_l = (u16*)(smem + 30720);

  const int t = threadIdx.x;
  // T1 XCD-chunked swizzle (grid 1024 % 8 == 0 -> bijective): ID-contiguous
  // work shares one XCD's L2, so the 4 n-tile blocks of one m-tile (shared
  // A-panel, 393 KB) and the W1 panel (1.5 MB < 4 MB L2) get L2 reuse.
  const int wid = ((blockIdx.x & 7) << 7) + (blockIdx.x >> 3);
  const int tile_m = wid >> 2, tile_n = wid & 3;
  const int m0 = tile_m * 128, n0 = tile_n * 128;
  const int w = t >> 6, l = t & 63;
  const int wr = w >> 1, wc = w & 1;
  const int lm = l & 15, lk = (l >> 4) * 8, q = l >> 4;
  const int srow = t >> 1, skh = (t & 1) * 16;

  const u16* Agh = xh + (m0 + srow) * Dd + skh;
  const u16* Agl = xl + (m0 + srow) * Dd + skh;
  const u16* Bgh = w1h + (n0 + srow) * Dd + skh;
  const u16* Bgl = w1l + (n0 + srow) * Dd + skh;

  float b1v[4];
#pragma unroll
  for (int n = 0; n < 4; ++n) b1v[n] = b1[n0 + wc * 64 + n * 16 + lm];

  f32x4 acc[4][4] = {};

#pragma unroll 1
  for (int kt = 0; kt < Dd / 32; ++kt) {
    const int k0 = kt * 32;
    uint4 ah0 = *(const uint4*)(Agh + k0), ah1 = *(const uint4*)(Agh + k0 + 8);
    uint4 al0 = *(const uint4*)(Agl + k0), al1 = *(const uint4*)(Agl + k0 + 8);
    uint4 bh0 = *(const uint4*)(Bgh + k0), bh1 = *(const uint4*)(Bgh + k0 + 8);
    uint4 bl0 = *(const uint4*)(Bgl + k0), bl1 = *(const uint4*)(Bgl + k0 + 8);
    __syncthreads();  // previous iteration's frag reads done
    *(uint4*)&As_h[srow * 40 + skh] = ah0; *(uint4*)&As_h[srow * 40 + skh + 8] = ah1;
    *(uint4*)&As_l[srow * 40 + skh] = al0; *(uint4*)&As_l[srow * 40 + skh + 8] = al1;
    *(uint4*)&Bs_h[srow * 40 + skh] = bh0; *(uint4*)&Bs_h[srow * 40 + skh + 8] = bh1;
    *(uint4*)&Bs_l[srow * 40 + skh] = bl0; *(uint4*)&Bs_l[srow * 40 + skh + 8] = bl1;
    __syncthreads();

    bf16x8 fah[4], fal[4], fbh[4], fbl[4];
#pragma unroll
    for (int m = 0; m < 4; ++m) {
      int ar = wr * 64 + m * 16 + lm;
      fah[m] = *(const bf16x8*)&As_h[ar * 40 + lk];
      fal[m] = *(const bf16x8*)&As_l[ar * 40 + lk];
    }
#pragma unroll
    for (int n = 0; n < 4; ++n) {
      int br = wc * 64 + n * 16 + lm;
      fbh[n] = *(const bf16x8*)&Bs_h[br * 40 + lk];
      fbl[n] = *(const bf16x8*)&Bs_l[br * 40 + lk];
    }
#pragma unroll
    for (int m = 0; m < 4; ++m)
#pragma unroll
      for (int n = 0; n < 4; ++n) {
        acc[m][n] = __builtin_amdgcn_mfma_f32_16x16x32_bf16(fah[m], fbh[n], acc[m][n], 0, 0, 0);
        acc[m][n] = __builtin_amdgcn_mfma_f32_16x16x32_bf16(fah[m], fbl[n], acc[m][n], 0, 0, 0);
        acc[m][n] = __builtin_amdgcn_mfma_f32_16x16x32_bf16(fal[m], fbh[n], acc[m][n], 0, 0, 0);
      }
  }

  // ---- fused epilogue: h-tile (bias+relu) -> Hs -> h@W2 chunk -> acc2 ----
  // FULLY UNROLLED: c must be compile-time so acc[m][n] is never runtime-indexed
  // (rule #20: runtime-indexed ext_vector arrays -> scratch; round-2: VGPR=52,
  // 2.9 GB scratch traffic per dispatch, 600 us).
  f32x4 acc2[2][3] = {};
#pragma unroll
  for (int c = 0; c < 4; ++c) {
    __syncthreads();  // protect last k-iter frag reads / previous c's Hs reads
    if (wc == (c >> 1)) {
#pragma unroll
      for (int nn = 0; nn < 2; ++nn) {
        int n = (c & 1) * 2 + nn;
        int k2 = nn * 16 + lm;   // 0..31 within chunk
#pragma unroll
        for (int m = 0; m < 4; ++m)
#pragma unroll
          for (int r = 0; r < 4; ++r) {
            int row = wr * 64 + m * 16 + q * 4 + r;
            Hs[row * 36 + k2] = fmaxf(acc[m][n][r] + b1v[n], 0.0f);
          }
      }
    }
    if (t < 192) {  // stage W2 chunk: rows 0..47 (tags), k-cols n0+c*32..+31
      int rr = t >> 2, kk = (t & 3) * 8;
      *(uint4*)&W2s_h[rr * 40 + kk] = *(const uint4*)(w2h + rr * Hh + n0 + c * 32 + kk);
      *(uint4*)&W2s_l[rr * 40 + kk] = *(const uint4*)(w2l + rr * Hh + n0 + c * 32 + kk);
    }
    __syncthreads();
#pragma unroll
    for (int j = 0; j < 2; ++j) {
      int mm = w * 2 + j;
      f32x4 h0 = *(const f32x4*)&Hs[(mm * 16 + lm) * 36 + lk];
      f32x4 h1 = *(const f32x4*)&Hs[(mm * 16 + lm) * 36 + lk + 4];
      float hv[8] = {h0[0], h0[1], h0[2], h0[3], h1[0], h1[1], h1[2], h1[3]};
      U4BF8 ah, al;
      u32 ll2[4], hh2[4];
#pragma unroll
      for (int i = 0; i < 4; ++i) hh2[i] = pack2(hv[2 * i], hv[2 * i + 1], ll2[i]);
      ah.u = make_uint4(hh2[0], hh2[1], hh2[2], hh2[3]);
      al.u = make_uint4(ll2[0], ll2[1], ll2[2], ll2[3]);
#pragma unroll
      for (int n2 = 0; n2 < 3; ++n2) {
        bf16x8 wh = *(const bf16x8*)&W2s_h[(n2 * 16 + lm) * 40 + lk];
        bf16x8 wl = *(const bf16x8*)&W2s_l[(n2 * 16 + lm) * 40 + lk];
        acc2[j][n2] = __builtin_amdgcn_mfma_f32_16x16x32_bf16(ah.v, wh, acc2[j][n2], 0, 0, 0);
        acc2[j][n2] = __builtin_amdgcn_mfma_f32_16x16x32_bf16(ah.v, wl, acc2[j][n2], 0, 0, 0);
        acc2[j][n2] = __builtin_amdgcn_mfma_f32_16x16x32_bf16(al.v, wh, acc2[j][n2], 0, 0, 0);
      }
    }
  }

  // logits partial: atomic accumulate (logits pre-initialized to b2)
#pragma unroll
  for (int j = 0; j < 2; ++j)
#pragma unroll
    for (int n2 = 0; n2 < 3; ++n2) {
      int col = n2 * 16 + lm;
      if (col < Tt) {
#pragma unroll
        for (int r = 0; r < 4; ++r) {
          int row = m0 + (w * 2 + j) * 16 + q * 4 + r;
          atomicAdd(logits + row * Tt + col, acc2[j][n2][r]);
        }
      }
    }
}

// ---------------- CRF forward + gold, one wave per batch elem ----------------
// readlane-broadcast matvec; rescale point = alpha[lane0] (spread across tags is O(1));
// result accumulated straight into out[0] (pre-zeroed by prep_all).
__global__ __launch_bounds__(64) void crf_kernel(
    const float* __restrict__ logits, const void* __restrict__ maskp,
    const int* __restrict__ labels, const float* __restrict__ trans,
    const float* __restrict__ start_t, const float* __restrict__ end_t,
    float* __restrict__ out) {
  const int b = blockIdx.x, l = threadIdx.x;
  const unsigned char* m8 = (const unsigned char*)maskp;
  const int* m32 = (const int*)maskp;
  // mask[0][1] is always true (lengths >= 256): u8 layout -> byte1 != 0; i32 -> byte1 == 0.
  const bool is_u8 = (m8[1] != 0);

  int cnt = 0;
#pragma unroll
  for (int s = l; s < Ss; s += 64) {
    int mv = is_u8 ? (int)m8[b * Ss + s] : m32[b * Ss + s];
    cnt += (mv != 0) ? 1 : 0;
  }
#pragma unroll
  for (int o = 32; o > 0; o >>= 1) cnt += __shfl_xor(cnt, o, 64);
  const int len = cnt;  // mask monotone: mask[s] == (s < len)

  const int* labs = labels + b * Ss;
  float g = 0.0f;
#pragma unroll
  for (int s = l; s < Ss; s += 64) {
    if (s < len) {
      int lab = labs[s];
      g += logits[(b * Ss + s) * Tt + lab];
      if (s + 1 < len) g += trans[lab * Tt + labs[s + 1]];
    }
  }
#pragma unroll
  for (int o = 32; o > 0; o >>= 1) g += __shfl_xor(g, o, 64);
  g += start_t[labs[0]] + end_t[labs[len - 1]];

  float Ecol[Tt];  // Ecol[i] = exp(trans[i][l])
#pragma unroll
  for (int i = 0; i < Tt; ++i)
    Ecol[i] = (l < Tt) ? __expf(trans[i * Tt + l]) : 0.0f;

  const float* lg = logits + b * Ss * Tt;
  float alpha = (l < Tt) ? (start_t[l] + lg[l]) : -INFINITY;
  float em_next = (l < Tt) ? lg[Tt + l] : 0.0f;

  for (int step = 1; step < len; ++step) {
    float em = em_next;
    int nxt = (step + 1 < len) ? step + 1 : len - 1;
    em_next = (l < Tt) ? lg[nxt * Tt + l] : 0.0f;   // prefetch: hidden under matvec
    float a0 = __uint_as_float(__builtin_amdgcn_readfirstlane(__float_as_uint(alpha)));
    float u = __expf(alpha - a0);   // lane0 -> 1; spread O(1), no overflow risk
    float s0 = 0.f, s1 = 0.f, s2 = 0.f, s3 = 0.f;
#pragma unroll
    for (int i = 0; i < 36; i += 4) {
      s0 = fmaf(rdlane(u, i + 0), Ecol[i + 0], s0);
      s1 = fmaf(rdlane(u, i + 1), Ecol[i + 1], s1);
      s2 = fmaf(rdlane(u, i + 2), Ecol[i + 2], s2);
      s3 = fmaf(rdlane(u, i + 3), Ecol[i + 3], s3);
    }
    s0 = fmaf(rdlane(u, 36), Ecol[36], s0);
    float sj = (s0 + s1) + (s2 + s3);
    alpha = a0 + __logf(sj) + em;   // lanes >= 37: value unused downstream
  }

  float v = (l < Tt) ? (alpha + end_t[l]) : -INFINITY;
  float M2 = v;
#pragma unroll
  for (int o = 32; o > 0; o >>= 1) M2 = fmaxf(M2, __shfl_xor(M2, o, 64));
  float e = __expf(v - M2);
#pragma unroll
  for (int o = 32; o > 0; o >>= 1) e += __shfl_xor(e, o, 64);
  float logZ = M2 + __logf(e);

  if (l == 0) atomicAdd(out, (logZ - g) * (1.0f / (float)Bb));
}

extern "C" void kernel_launch(void* const* d_in, const int* in_sizes, int n_in,
                              void* d_out, int out_size, void* d_ws, size_t ws_size,
                              hipStream_t stream) {
  const float* X       = (const float*)d_in[0];
  const void*  maskp   = d_in[1];
  const int*   labels  = (const int*)d_in[2];
  const float* W1      = (const float*)d_in[3];
  const float* b1      = (const float*)d_in[4];
  const float* W2      = (const float*)d_in[5];
  const float* b2      = (const float*)d_in[6];
  const float* trans   = (const float*)d_in[7];
  const float* start_t = (const float*)d_in[8];
  const float* end_t   = (const float*)d_in[9];
  float* out = (float*)d_out;

  char* ws = (char*)d_ws;
  size_t off = 0;
  u16* w1h = (u16*)(ws + off); off += (size_t)Hh * Dd * 2;          // 768 KB
  u16* w1l = (u16*)(ws + off); off += (size_t)Hh * Dd * 2;
  u16* w2h = (u16*)(ws + off); off += (size_t)48 * Hh * 2;          // 48 KB
  u16* w2l = (u16*)(ws + off); off += (size_t)48 * Hh * 2;
  u16* xh  = (u16*)(ws + off); off += (size_t)Bb * Ss * Dd * 2;     // 48 MB
  u16* xl  = (u16*)(ws + off); off += (size_t)Bb * Ss * Dd * 2;
  float* logits = (float*)(ws + off); off += (size_t)Bb * Ss * Tt * 4;  // 4.6 MB

  prep_all<<<PX + PW + PZ, 256, 0, stream>>>(X, W1, W2, b2, xh, xl, w1h, w1l, w2h, w2l, logits, out);
  gemm_fused<<<(Bb * Ss / 128) * (Hh / 128), 256, 0, stream>>>(xh, xl, w1h, w1l, b1, w2h, w2l, logits);
  crf_kernel<<<Bb, 64, 0, stream>>>(logits, maskp, labels, trans, start_t, end_t, out);
}